// Round 1
// baseline (2273.956 us; speedup 1.0000x reference)
//
#include <hip/hip_runtime.h>

#define M 4096
#define L 32
#define K 64
#define NBLK 256
#define BLOCK 1024
#define MK (M * K)

// One persistent cooperative-style kernel.
// Grid: 256 blocks x 1024 threads = 16 waves/block, 1 block/CU guaranteed
// resident (capacity is 2 blocks/CU at 16 waves each). Wave w of block b owns
// node m = 16*b + w; lane k owns the k-th in-edge.
// Layer-to-layer exchange: v vector (16 KB) double-buffered in d_ws; each
// block re-stages the full vector into LDS after each global barrier.
__global__ __launch_bounds__(BLOCK, 4)
void net_kernel(const float* __restrict__ x,
                const float* __restrict__ w_in,
                const float* __restrict__ b_in,
                const float* __restrict__ w,
                const float* __restrict__ b,
                const int* __restrict__ igraf,
                float* __restrict__ out,
                unsigned* __restrict__ cnt,
                float* __restrict__ gbuf)
{
    __shared__ float sv[M];   // full previous-layer value vector (16 KB)

    const int tid  = threadIdx.x;
    const int blk  = blockIdx.x;
    const int wave = tid >> 6;
    const int lane = tid & 63;
    const int m    = blk * 16 + wave;          // node owned by this wave
    const bool lastblk = (blk == NBLK - 1);    // owns node M-1

    // Prefetch layer-0 fragments first so they're in flight during v0 compute.
    float wreg;
    int   ireg;
    {
        const size_t base0 = (size_t)m * K + (size_t)lane;
        wreg = w[base0];
        ireg = igraf[base0];
    }

    // v0 = relu(w_in * x + b_in), computed redundantly per block into LDS.
    {
        const float4 x4 = ((const float4*)x)[tid];
        const float4 wi = ((const float4*)w_in)[tid];
        const float4 bi = ((const float4*)b_in)[tid];
        float4 r;
        r.x = fmaxf(fmaf(wi.x, x4.x, bi.x), 0.0f);
        r.y = fmaxf(fmaf(wi.y, x4.y, bi.y), 0.0f);
        r.z = fmaxf(fmaf(wi.z, x4.z, bi.z), 0.0f);
        r.w = fmaxf(fmaf(wi.w, x4.w, bi.w), 0.0f);
        ((float4*)sv)[tid] = r;
    }
    __syncthreads();

    for (int l = 0; l < L; ++l) {
        // Gather + product for this layer (uses regs prefetched last iter).
        float p = wreg * sv[ireg];

        // Prefetch next layer's fragment before the barrier so the spin time
        // hides the load latency. Layer L-1 is only needed by block 255.
        if ((l + 1 < L) && ((l + 1 < L - 1) || lastblk)) {
            const size_t nb = (size_t)(l + 1) * MK + (size_t)m * K + (size_t)lane;
            wreg = w[nb];
            ireg = igraf[nb];
        }

        // Wave reduction over K=64 lanes.
        #pragma unroll
        for (int off = 32; off > 0; off >>= 1)
            p += __shfl_xor(p, off, 64);

        if (lane == 0) {
            const float t = p + b[l * M + m];
            const float s = 1.0f / (1.0f + __expf(-t));
            if (l < L - 1) {
                gbuf[((l + 1) & 1) * M + m] = s;   // publish to exchange buffer
            } else if (m == M - 1) {
                out[0] = s;                         // final scalar
            }
        }
        if (l == L - 1) break;

        // ---- device-wide barrier #(l+1), monotonic counter ----
        __syncthreads();
        if (tid == 0) {
            __threadfence();  // release: make this block's v write agent-visible
            __hip_atomic_fetch_add(cnt, 1u, __ATOMIC_RELAXED,
                                   __HIP_MEMORY_SCOPE_AGENT);
            // Non-last blocks at the final barrier only need to arrive.
            const bool needspin = (l < L - 2) || lastblk;
            if (needspin) {
                const unsigned tgt = (unsigned)NBLK * (unsigned)(l + 1);
                while (__hip_atomic_load(cnt, __ATOMIC_RELAXED,
                                         __HIP_MEMORY_SCOPE_AGENT) < tgt)
                    __builtin_amdgcn_s_sleep(1);
            }
        }
        __syncthreads();
        if ((l == L - 2) && !lastblk) return;  // done: only block 255 runs layer 31
        __threadfence();  // acquire: invalidate L1/L2 so staging sees fresh v

        // Re-stage the new v vector into LDS (one float4 per thread = 16 KB).
        ((float4*)sv)[tid] = ((const float4*)(gbuf + ((l + 1) & 1) * M))[tid];
        __syncthreads();
    }
}

extern "C" void kernel_launch(void* const* d_in, const int* in_sizes, int n_in,
                              void* d_out, int out_size, void* d_ws, size_t ws_size,
                              hipStream_t stream) {
    const float* x     = (const float*)d_in[0];
    const float* w_in  = (const float*)d_in[1];
    const float* b_in  = (const float*)d_in[2];
    const float* w     = (const float*)d_in[3];
    const float* b     = (const float*)d_in[4];
    const int*   igraf = (const int*)d_in[5];
    float*       out   = (float*)d_out;

    unsigned* cnt  = (unsigned*)d_ws;                    // barrier counter
    float*    gbuf = (float*)((char*)d_ws + 256);        // 2 x M floats exchange

    // ws is poisoned 0xAA before every timed launch: zero the barrier counter.
    hipMemsetAsync(d_ws, 0, 256, stream);

    void* args[] = {(void*)&x, (void*)&w_in, (void*)&b_in, (void*)&w,
                    (void*)&b, (void*)&igraf, (void*)&out, (void*)&cnt,
                    (void*)&gbuf};
    hipLaunchKernelGGL(net_kernel, dim3(NBLK), dim3(BLOCK), 0, stream,
                       x, w_in, b_in, w, b, igraf, out, cnt, gbuf);
    (void)args; (void)in_sizes; (void)n_in; (void)out_size; (void)ws_size;
}

// Round 2
// 297.275 us; speedup vs baseline: 7.6493x; 7.6493x over previous
//
#include <hip/hip_runtime.h>

#define M 4096
#define L 32
#define K 64
#define NBLK 256
#define BLOCK 1024
#define MK (M * K)

// Persistent kernel, one global barrier per layer.
// Grid: 256 blocks x 1024 threads (16 waves). Wave w of block b owns node
// m = 16*b + w; lane k owns in-edge k. v exchanged via double-buffered gbuf.
//
// Barrier design (R1): no __threadfence anywhere.
//  - publish: lane0 agent-scope atomic store (write-through, visible at L3)
//  - __syncthreads drains vmcnt(0) per wave -> stores globally visible
//  - tid0: relaxed agent fetch_add on arrival counter (line A)
//  - last arriver stores release=round (line B, separate cacheline)
//  - spinners poll line B with s_sleep(8) backoff; then ONE acquire atomic
//    load emits the L1/L2 invalidate for the whole block (hardware cache op)
__global__ __launch_bounds__(BLOCK, 4)
void net_kernel(const float* __restrict__ x,
                const float* __restrict__ w_in,
                const float* __restrict__ b_in,
                const float* __restrict__ w,
                const float* __restrict__ b,
                const int* __restrict__ igraf,
                float* __restrict__ out,
                unsigned* __restrict__ cnt,
                unsigned* __restrict__ release,
                float* __restrict__ gbuf)
{
    __shared__ float sv[M];   // full previous-layer value vector (16 KB)

    const int tid  = threadIdx.x;
    const int blk  = blockIdx.x;
    const int wave = tid >> 6;
    const int lane = tid & 63;
    const int m    = blk * 16 + wave;
    const bool lastblk = (blk == NBLK - 1);   // owns node M-1

    // Prefetch layer-0 fragments + bias.
    float wreg;
    int   ireg;
    {
        const size_t base0 = (size_t)m * K + (size_t)lane;
        wreg = w[base0];
        ireg = igraf[base0];
    }
    float breg = b[m];   // b[0*M + m]

    // v0 = relu(w_in * x + b_in), redundant per block, straight into LDS.
    {
        const float4 x4 = ((const float4*)x)[tid];
        const float4 wi = ((const float4*)w_in)[tid];
        const float4 bi = ((const float4*)b_in)[tid];
        float4 r;
        r.x = fmaxf(fmaf(wi.x, x4.x, bi.x), 0.0f);
        r.y = fmaxf(fmaf(wi.y, x4.y, bi.y), 0.0f);
        r.z = fmaxf(fmaf(wi.z, x4.z, bi.z), 0.0f);
        r.w = fmaxf(fmaf(wi.w, x4.w, bi.w), 0.0f);
        ((float4*)sv)[tid] = r;
    }
    __syncthreads();

    for (int l = 0; l < L; ++l) {
        // Gather + product (regs prefetched last iteration).
        float p = wreg * sv[ireg];

        // Prefetch next layer before the barrier; spin time hides latency.
        const bool need_next = (l + 1 < L) && ((l + 1 < L - 1) || lastblk);
        float bnext = 0.0f;
        if (need_next) {
            const size_t nb = (size_t)(l + 1) * MK + (size_t)m * K + (size_t)lane;
            wreg  = w[nb];
            ireg  = igraf[nb];
            bnext = b[(l + 1) * M + m];
        }

        // Wave reduction over K=64 lanes.
        #pragma unroll
        for (int off = 32; off > 0; off >>= 1)
            p += __shfl_xor(p, off, 64);

        if (lane == 0) {
            const float t = p + breg;
            const float s = 1.0f / (1.0f + __expf(-t));
            if (l < L - 1) {
                // Agent-scope write-through publish: no release fence needed.
                __hip_atomic_store(&gbuf[((l + 1) & 1) * M + m], s,
                                   __ATOMIC_RELAXED, __HIP_MEMORY_SCOPE_AGENT);
            } else if (m == M - 1) {
                out[0] = s;
            }
        }
        breg = bnext;
        if (l == L - 1) break;

        // ---- device-wide barrier, round r = l+1 ----
        __syncthreads();   // drains every wave's vmcnt -> publishes visible
        if (tid == 0) {
            const unsigned r = (unsigned)(l + 1);
            const unsigned old = __hip_atomic_fetch_add(
                cnt, 1u, __ATOMIC_RELAXED, __HIP_MEMORY_SCOPE_AGENT);
            if (old == (unsigned)NBLK * r - 1u) {
                // last arriver: open the gate
                __hip_atomic_store(release, r, __ATOMIC_RELAXED,
                                   __HIP_MEMORY_SCOPE_AGENT);
            } else {
                const bool needspin = (l < L - 2) || lastblk;
                if (needspin) {
                    while (__hip_atomic_load(release, __ATOMIC_RELAXED,
                                             __HIP_MEMORY_SCOPE_AGENT) < r)
                        __builtin_amdgcn_s_sleep(8);
                }
            }
            // One acquire per block per layer: emits L1/L2 invalidate so the
            // restage below reads fresh v. Cache ops retire via vmcnt, and
            // __syncthreads waits vmcnt(0), so the inv completes before any
            // other wave's restage load issues.
            (void)__hip_atomic_load(release, __ATOMIC_ACQUIRE,
                                    __HIP_MEMORY_SCOPE_AGENT);
        }
        __syncthreads();
        if ((l == L - 2) && !lastblk) return;  // only block 255 runs layer 31

        // Re-stage new v into LDS (one float4/thread = 16 KB, normal loads).
        ((float4*)sv)[tid] = ((const float4*)(gbuf + ((l + 1) & 1) * M))[tid];
        __syncthreads();
    }
}

extern "C" void kernel_launch(void* const* d_in, const int* in_sizes, int n_in,
                              void* d_out, int out_size, void* d_ws, size_t ws_size,
                              hipStream_t stream) {
    const float* x     = (const float*)d_in[0];
    const float* w_in  = (const float*)d_in[1];
    const float* b_in  = (const float*)d_in[2];
    const float* w     = (const float*)d_in[3];
    const float* b     = (const float*)d_in[4];
    const int*   igraf = (const int*)d_in[5];
    float*       out   = (float*)d_out;

    unsigned* cnt     = (unsigned*)d_ws;                     // line A
    unsigned* release = (unsigned*)((char*)d_ws + 1024);     // line B
    float*    gbuf    = (float*)((char*)d_ws + 4096);        // 2 x M floats

    // ws is re-poisoned 0xAA before every timed launch: zero barrier state.
    hipMemsetAsync(d_ws, 0, 4096, stream);

    hipLaunchKernelGGL(net_kernel, dim3(NBLK), dim3(BLOCK), 0, stream,
                       x, w_in, b_in, w, b, igraf, out, cnt, release, gbuf);
    (void)in_sizes; (void)n_in; (void)out_size; (void)ws_size;
}

// Round 3
// 207.347 us; speedup vs baseline: 10.9669x; 1.4337x over previous
//
#include <hip/hip_runtime.h>

#define M 4096
#define L 32
#define K 64
#define NBLK 256
#define BLOCK 1024
#define MK (M * K)
#define NLEAF 32
#define LEAF_STRIDE 64   // unsigned units -> 256 B between barrier lines

// Persistent kernel, one global barrier per layer.
// Wave w of block b owns node m = 16*b + w; lane k owns in-edge k.
//
// Barrier (R2): NO acquire fence / buffer_inv anywhere.
//  - gbuf is accessed ONLY via agent-scope atomics (sc1, cache-bypassing),
//    so no stale L1/L2 copies can exist; restage reads L3 directly.
//  - arrival: 2-level tree (32 leaves x 8 blocks -> root) to cut same-line
//    atomic serialization 256 -> 32.
//  - next-layer prefetch issued AFTER the publish-drain syncthreads so its
//    vmcnt drain overlaps the spin window instead of delaying arrival.
__global__ __launch_bounds__(BLOCK, 4)
void net_kernel(const float* __restrict__ x,
                const float* __restrict__ w_in,
                const float* __restrict__ b_in,
                const float* __restrict__ w,
                const float* __restrict__ b,
                const int* __restrict__ igraf,
                float* __restrict__ out,
                unsigned* __restrict__ bar,
                float* __restrict__ gbuf)
{
    __shared__ float sv[M];   // full previous-layer value vector (16 KB)

    const int tid  = threadIdx.x;
    const int blk  = blockIdx.x;
    const int wave = tid >> 6;
    const int lane = tid & 63;
    const int m    = blk * 16 + wave;
    const bool lastblk = (blk == NBLK - 1);   // owns node M-1

    unsigned* leaf    = bar + (blk >> 3) * LEAF_STRIDE;
    unsigned* root    = bar + NLEAF * LEAF_STRIDE;
    unsigned* release = root + LEAF_STRIDE;

    // Layer-0 fragment prefetch.
    float wreg; int ireg; float breg;
    {
        const size_t base0 = (size_t)m * K + (size_t)lane;
        wreg = w[base0];
        ireg = igraf[base0];
        breg = b[m];
    }

    // v0 = relu(w_in * x + b_in), redundant per block, into LDS.
    {
        const float4 x4 = ((const float4*)x)[tid];
        const float4 wi = ((const float4*)w_in)[tid];
        const float4 bi = ((const float4*)b_in)[tid];
        float4 r;
        r.x = fmaxf(fmaf(wi.x, x4.x, bi.x), 0.0f);
        r.y = fmaxf(fmaf(wi.y, x4.y, bi.y), 0.0f);
        r.z = fmaxf(fmaf(wi.z, x4.z, bi.z), 0.0f);
        r.w = fmaxf(fmaf(wi.w, x4.w, bi.w), 0.0f);
        ((float4*)sv)[tid] = r;
    }
    __syncthreads();

    for (int l = 0; l < L; ++l) {
        // Gather + product (regs prefetched during previous spin window).
        float p = wreg * sv[ireg];

        // Wave reduction over K=64 lanes.
        #pragma unroll
        for (int off = 32; off > 0; off >>= 1)
            p += __shfl_xor(p, off, 64);

        if (lane == 0) {
            const float t = p + breg;
            const float s = 1.0f / (1.0f + __expf(-t));
            if (l < L - 1) {
                // Agent-scope write-through publish (visible at L3).
                __hip_atomic_store(&gbuf[((l + 1) & 1) * M + m], s,
                                   __ATOMIC_RELAXED, __HIP_MEMORY_SCOPE_AGENT);
            } else if (m == M - 1) {
                out[0] = s;
            }
        }
        if (l == L - 1) break;

        __syncthreads();   // drains vmcnt -> all 16 publishes visible at L3

        // Prefetch next layer's fragments now: their completion-wait lands on
        // the next syncthreads, which overlaps the barrier spin window.
        if ((l + 2 < L) || lastblk) {
            const size_t nb = (size_t)(l + 1) * MK + (size_t)m * K + (size_t)lane;
            wreg = w[nb];
            ireg = igraf[nb];
            breg = b[(l + 1) * M + m];
        }

        if (tid == 0) {
            const unsigned r = (unsigned)(l + 1);
            unsigned old = __hip_atomic_fetch_add(
                leaf, 1u, __ATOMIC_RELAXED, __HIP_MEMORY_SCOPE_AGENT);
            if (old == 8u * r - 1u) {
                old = __hip_atomic_fetch_add(
                    root, 1u, __ATOMIC_RELAXED, __HIP_MEMORY_SCOPE_AGENT);
                if (old == (unsigned)NLEAF * r - 1u) {
                    __hip_atomic_store(release, r, __ATOMIC_RELAXED,
                                       __HIP_MEMORY_SCOPE_AGENT);
                }
            }
            const bool needspin = (l < L - 2) || lastblk;
            if (needspin) {
                while (__hip_atomic_load(release, __ATOMIC_RELAXED,
                                         __HIP_MEMORY_SCOPE_AGENT) < r)
                    __builtin_amdgcn_s_sleep(4);
            }
        }
        __syncthreads();   // waves held until release; prefetch drains here
        if ((l == L - 2) && !lastblk) return;  // only block 255 runs layer 31

        // Re-stage new v into LDS via agent-scope (cache-bypassing) loads.
        // Stride-BLOCK layout: each instruction perfectly coalesced.
        {
            float* src = gbuf + ((l + 1) & 1) * M;
            #pragma unroll
            for (int j = 0; j < 4; ++j) {
                const int idx = tid + j * BLOCK;
                sv[idx] = __hip_atomic_load(&src[idx], __ATOMIC_RELAXED,
                                            __HIP_MEMORY_SCOPE_AGENT);
            }
        }
        __syncthreads();
    }
}

extern "C" void kernel_launch(void* const* d_in, const int* in_sizes, int n_in,
                              void* d_out, int out_size, void* d_ws, size_t ws_size,
                              hipStream_t stream) {
    const float* x     = (const float*)d_in[0];
    const float* w_in  = (const float*)d_in[1];
    const float* b_in  = (const float*)d_in[2];
    const float* w     = (const float*)d_in[3];
    const float* b     = (const float*)d_in[4];
    const int*   igraf = (const int*)d_in[5];
    float*       out   = (float*)d_out;

    unsigned* bar  = (unsigned*)d_ws;                 // leaves + root + release
    float*    gbuf = (float*)((char*)d_ws + 16384);   // 2 x M floats exchange

    // ws is re-poisoned 0xAA before every timed launch: zero barrier state.
    hipMemsetAsync(d_ws, 0, 16384, stream);

    hipLaunchKernelGGL(net_kernel, dim3(NBLK), dim3(BLOCK), 0, stream,
                       x, w_in, b_in, w, b, igraf, out, bar, gbuf);
    (void)in_sizes; (void)n_in; (void)out_size; (void)ws_size;
}